// Round 19
// baseline (343.551 us; speedup 1.0000x reference)
//
#include <hip/hip_runtime.h>
#include <math.h>

#define NPIX 524288   // 8*256*256

typedef __attribute__((ext_vector_type(8))) short short8b;
typedef __attribute__((ext_vector_type(4))) float f32x4;
#define MFMA16 __builtin_amdgcn_mfma_f32_16x16x32_bf16

__device__ inline unsigned short bf16_rn(float x) {
    unsigned u = __float_as_uint(x);
    unsigned r = (u + 0x7FFFu + ((u >> 16) & 1u)) >> 16;
    return (unsigned short)r;
}
__device__ inline float bf16_f(unsigned short h) {
    return __uint_as_float(((unsigned)h) << 16);
}
// truncation split for weight hi/lo pairs
__device__ inline void tsplit1(float a, unsigned short& h, unsigned short& l) {
    unsigned u = __float_as_uint(a);
    h = (unsigned short)(u >> 16);
    float r = a - __uint_as_float(u & 0xFFFF0000u);
    l = (unsigned short)(__float_as_uint(r) >> 16);
}

// ---------- kernel 1a: collapse offset head
__global__ void build_wcomb_kernel(const float* __restrict__ Woff1,
                                   const float* __restrict__ boff1,
                                   const float* __restrict__ Woff2,
                                   float* __restrict__ wcomb,
                                   float* __restrict__ bcomb) {
    int idx = blockIdx.x * 256 + threadIdx.x;
    if (idx < 2 * 64 * 25) {
        int p = idx / 1600;
        int rest = idx - p * 1600;
        float s = 0.f;
        for (int cm = 0; cm < 64; ++cm)
            s += Woff2[p * 64 + cm] * Woff1[cm * 1600 + rest];
        wcomb[idx] = s;
    }
    if (idx < 2) {
        float s = 0.f;
        for (int cm = 0; cm < 64; ++cm) s += Woff2[idx * 64 + cm] * boff1[cm];
        bcomb[idx] = s;
    }
}

// ---------- kernel 1b: Wcat[128][64] = [0.125*Wq ; Wproj@Wq ; 0] as bf16 hi/lo + fp32 bcat
__global__ void build_wcat_kernel(const float* __restrict__ Wq, const float* __restrict__ bq,
                                  const float* __restrict__ wcomb,
                                  unsigned short* __restrict__ wcath,
                                  unsigned short* __restrict__ wcatl,
                                  float* __restrict__ bcat) {
    int idx = blockIdx.x * 256 + threadIdx.x;
    if (idx < 8192) {
        int r = idx >> 6, c = idx & 63;
        float v = 0.f;
        if (r < 64) v = Wq[r * 64 + c] * 0.125f;
        else if (r < 114) {
            int ch = r - 64, p = ch / 25, tap = ch % 25;
            for (int cin = 0; cin < 64; ++cin)
                v += wcomb[p * 1600 + cin * 25 + tap] * Wq[cin * 64 + c];
        }
        unsigned short hh, ll;
        tsplit1(v, hh, ll);
        wcath[idx] = hh;
        wcatl[idx] = ll;
    }
    if (idx >= 8192 && idx < 8192 + 128) {
        int r = idx - 8192;
        float v = 0.f;
        if (r < 64) v = bq[r] * 0.125f;
        else if (r < 114) {
            int ch = r - 64, p = ch / 25, tap = ch % 25;
            for (int cin = 0; cin < 64; ++cin)
                v += wcomb[p * 1600 + cin * 25 + tap] * bq[cin];
        }
        bcat[r] = v;
    }
}

// ---------- kernel 1c: fixed weights -> bf16 hi/lo planes
__global__ void build_wfixed_kernel(const float* __restrict__ Wk, const float* __restrict__ Wv,
                                    const float* __restrict__ Wout,
                                    unsigned short* __restrict__ wkvh, unsigned short* __restrict__ wkvl,
                                    unsigned short* __restrict__ wouth, unsigned short* __restrict__ woutl) {
    int idx = blockIdx.x * 256 + threadIdx.x;
    if (idx < 8192) {
        float v = (idx < 4096) ? Wk[idx] : Wv[idx - 4096];
        unsigned short hh, ll;
        tsplit1(v, hh, ll);
        wkvh[idx] = hh;
        wkvl[idx] = ll;
    } else if (idx < 12288) {
        float v = Wout[idx - 8192];
        unsigned short hh, ll;
        tsplit1(v, hh, ll);
        wouth[idx - 8192] = hh;
        woutl[idx - 8192] = ll;
    }
}

// ---------- kernel 2: fused q + proj conv via MFMA; emits xb16; q/proj staged in LDS
__global__ __launch_bounds__(256)
void convqp_kernel(const float* __restrict__ in, const unsigned short* __restrict__ wh,
                   const unsigned short* __restrict__ wl, const float* __restrict__ bcat,
                   unsigned short* __restrict__ qh, unsigned short* __restrict__ projout,
                   unsigned short* __restrict__ xb16) {
    __shared__ unsigned short lds[8704];     // 17408 B
    unsigned short* a_s  = lds;              // [64][72] (input staging + MFMA A)
    unsigned short* stg2 = lds;              // [114][68] overlay after MFMA
    int t = threadIdx.x;
    int p = t & 63, w = t >> 6;
    int pix0 = blockIdx.x * 64;
    {
        const float4* src = (const float4*)(in + (size_t)(pix0 + p) * 64 + w * 16);
#pragma unroll
        for (int u4 = 0; u4 < 4; ++u4) {
            float4 v = src[u4];
            ushort4 hv;
            hv.x = bf16_rn(v.x); hv.y = bf16_rn(v.y);
            hv.z = bf16_rn(v.z); hv.w = bf16_rn(v.w);
            *(ushort4*)&a_s[p * 72 + w * 16 + u4 * 4] = hv;
        }
    }
    __syncthreads();
    {   // coalesced xb16 store: thread (pgx = t>>2, wgx = t&3) writes 32B
        int pgx = t >> 2, wgx = t & 3;
        const unsigned short* srcx = &a_s[pgx * 72 + wgx * 16];
        unsigned short* dstx = xb16 + (size_t)(pix0 + pgx) * 64 + wgx * 16;
        *(short8b*)(dstx)     = *(const short8b*)(srcx);
        *(short8b*)(dstx + 8) = *(const short8b*)(srcx + 8);
    }
    int lrow = t & 15, lgrp = (t & 63) >> 4;
    int wc = w * 32;
    f32x4 acc[4][2];
#pragma unroll
    for (int mi = 0; mi < 4; ++mi)
#pragma unroll
        for (int nj = 0; nj < 2; ++nj) acc[mi][nj] = (f32x4){0.f, 0.f, 0.f, 0.f};
#pragma unroll
    for (int dk = 0; dk < 2; ++dk) {
        int k0 = dk * 32 + lgrp * 8;
        short8b bh[2], bl[2];
#pragma unroll
        for (int nj = 0; nj < 2; ++nj) {
            int c = wc + nj * 16 + lrow;
            bh[nj] = *(const short8b*)(wh + c * 64 + k0);
            bl[nj] = *(const short8b*)(wl + c * 64 + k0);
        }
#pragma unroll
        for (int mi = 0; mi < 4; ++mi) {
            int r = mi * 16 + lrow;
            short8b ah = *(short8b*)&a_s[r * 72 + k0];
#pragma unroll
            for (int nj = 0; nj < 2; ++nj) {
                acc[mi][nj] = MFMA16(ah, bh[nj], acc[mi][nj], 0, 0, 0);
                acc[mi][nj] = MFMA16(ah, bl[nj], acc[mi][nj], 0, 0, 0);
            }
        }
    }
    __syncthreads();   // all a_s reads done -> stg2 may overwrite
#pragma unroll
    for (int nj = 0; nj < 2; ++nj) {
        int c = wc + nj * 16 + lrow;
        if (c < 114) {
            float bias = bcat[c];
#pragma unroll
            for (int mi = 0; mi < 4; ++mi) {
                ushort4 hv;
                hv.x = bf16_rn(acc[mi][nj][0] + bias);
                hv.y = bf16_rn(acc[mi][nj][1] + bias);
                hv.z = bf16_rn(acc[mi][nj][2] + bias);
                hv.w = bf16_rn(acc[mi][nj][3] + bias);
                *(ushort4*)&stg2[c * 68 + mi * 16 + lgrp * 4] = hv;
            }
        }
    }
    __syncthreads();
    if (t < 228) {   // 64B-chunk coalesced plane writes
        int c = t >> 1, half = t & 1;
        int b = pix0 >> 16, hw0 = pix0 & 65535;
        const unsigned short* src = &stg2[c * 68 + half * 32];
        unsigned short* dst = (c < 64)
            ? qh + (((size_t)(b * 64 + c)) << 16) + hw0 + half * 32
            : projout + (((size_t)(b * 50 + (c - 64))) << 16) + hw0 + half * 32;
#pragma unroll
        for (int r2 = 0; r2 < 4; ++r2)
            *(short8b*)(dst + r2 * 8) = *(const short8b*)(src + r2 * 8);
    }
}

// ---------- kernel 3: offset via 25-tap shift-add over bf16 proj planes -> sample coords
__global__ __launch_bounds__(256)
void offset_gather_kernel(const unsigned short* __restrict__ proj, const float* __restrict__ bcomb,
                          float2* __restrict__ coords) {
    int x = threadIdx.x, y = blockIdx.x, b = blockIdx.y;
    const unsigned short* pb = proj + (((size_t)b * 50) << 16);
    float a0 = bcomb[0], a1 = bcomb[1];
#pragma unroll
    for (int ky = 0; ky < 5; ++ky) {
        int yy = y + ky - 2;
        if (yy < 0 || yy >= 256) continue;
#pragma unroll
        for (int kx = 0; kx < 5; ++kx) {
            int xx = x + kx - 2;
            if (xx < 0 || xx >= 256) continue;
            int tap = ky * 5 + kx;
            size_t off = (size_t)yy * 256 + xx;
            a0 += bf16_f(pb[((size_t)tap << 16) + off]);
            a1 += bf16_f(pb[((size_t)(25 + tap) << 16) + off]);
        }
    }
    float ox = tanhf(a0) * 5.f, oy = tanhf(a1) * 5.f;
    float vgx = (float)x + ox, vgy = (float)y + oy;
    float ix = vgx * (256.f / 255.f) - 0.5f;
    float iy = vgy * (256.f / 255.f) - 0.5f;
    coords[(((size_t)b) << 16) + y * 256 + x] = make_float2(ix, iy);
}

// ---------- kernel 4: 8x8-patch bilinear sample (bf16 x) + k/v convs via MFMA
__global__ __launch_bounds__(256)
void sample_kv_kernel(const unsigned short* __restrict__ xb16, const float2* __restrict__ coords,
                      const unsigned short* __restrict__ wh, const unsigned short* __restrict__ wl,
                      const float* __restrict__ bk, const float* __restrict__ bv,
                      const float* __restrict__ rpb,
                      unsigned short* __restrict__ khi, unsigned short* __restrict__ vthi) {
    __shared__ char smem[18432 + 2048];
    unsigned short* a_s = (unsigned short*)smem;             // [64][72] single plane
    unsigned short* stg = (unsigned short*)smem;             // 2 x [64][72] overlays a after barrier
    float* rpbl = (float*)(smem + 18432);                    // [64 c][8 h]

    int t = threadIdx.x;
    int b = blockIdx.x >> 10, pidx = blockIdx.x & 1023;
    int h0 = (pidx >> 5) * 8, w0 = (pidx & 31) * 8;
    int w = t >> 6;
    {   // stage rpb slice
        int i0 = t * 2;
        rpbl[i0]     = rpb[(i0 >> 3) * 256 + h0 + (i0 & 7)];
        rpbl[i0 + 1] = rpb[((i0 + 1) >> 3) * 256 + h0 + ((i0 + 1) & 7)];
    }
    {   // gather from bf16 x: pg = pixel (t>>2), wg = chan-quarter (t&3)
        int pg = t >> 2, wg = t & 3;
        int dyg = pg >> 3, dxg = pg & 7;
        int hwg = (h0 + dyg) * 256 + (w0 + dxg);
        float2 cc = coords[(((size_t)b) << 16) + hwg];
        float ix0f = floorf(cc.x), iy0f = floorf(cc.y);
        float wx1 = cc.x - ix0f, wy1 = cc.y - iy0f;
        float wx0 = 1.f - wx1, wy0 = 1.f - wy1;
        int ix0 = (int)ix0f, iy0 = (int)iy0f;
        float s[16];
#pragma unroll
        for (int u = 0; u < 16; ++u) s[u] = 0.f;
        const unsigned short* xb = xb16 + ((((size_t)b) << 16) << 6) + wg * 16;
        int cxs[4] = {ix0, ix0 + 1, ix0, ix0 + 1};
        int cys[4] = {iy0, iy0, iy0 + 1, iy0 + 1};
        float ws4[4] = {wx0 * wy0, wx1 * wy0, wx0 * wy1, wx1 * wy1};
#pragma unroll
        for (int cr = 0; cr < 4; ++cr) {
            int cx = cxs[cr], cy = cys[cr];
            if (cx >= 0 && cx < 256 && cy >= 0 && cy < 256) {
                float wgt = ws4[cr];
                const short8b* sp = (const short8b*)(xb + ((size_t)(cy * 256 + cx) << 6));
                short8b v0 = sp[0];
                short8b v1 = sp[1];
#pragma unroll
                for (int u = 0; u < 8; ++u) {
                    s[u]     += wgt * bf16_f((unsigned short)v0[u]);
                    s[u + 8] += wgt * bf16_f((unsigned short)v1[u]);
                }
            }
        }
#pragma unroll
        for (int u4 = 0; u4 < 4; ++u4) {
            ushort4 hv;
            hv.x = bf16_rn(s[u4 * 4]);     hv.y = bf16_rn(s[u4 * 4 + 1]);
            hv.z = bf16_rn(s[u4 * 4 + 2]); hv.w = bf16_rn(s[u4 * 4 + 3]);
            *(ushort4*)&a_s[pg * 72 + wg * 16 + u4 * 4] = hv;
        }
    }
    __syncthreads();
    int lrow = t & 15, lgrp = (t & 63) >> 4;
    int wc = w * 32;
    f32x4 acc[4][2];
#pragma unroll
    for (int mi = 0; mi < 4; ++mi)
#pragma unroll
        for (int nj = 0; nj < 2; ++nj) acc[mi][nj] = (f32x4){0.f, 0.f, 0.f, 0.f};
#pragma unroll
    for (int dk = 0; dk < 2; ++dk) {
        int k0 = dk * 32 + lgrp * 8;
        short8b bh[2], bl[2];
#pragma unroll
        for (int nj = 0; nj < 2; ++nj) {
            int c = wc + nj * 16 + lrow;
            bh[nj] = *(const short8b*)(wh + c * 64 + k0);
            bl[nj] = *(const short8b*)(wl + c * 64 + k0);
        }
#pragma unroll
        for (int mi = 0; mi < 4; ++mi) {
            int r = mi * 16 + lrow;
            short8b ah = *(short8b*)&a_s[r * 72 + k0];
#pragma unroll
            for (int nj = 0; nj < 2; ++nj) {
                acc[mi][nj] = MFMA16(ah, bh[nj], acc[mi][nj], 0, 0, 0);
                acc[mi][nj] = MFMA16(ah, bl[nj], acc[mi][nj], 0, 0, 0);
            }
        }
    }
    __syncthreads();   // a reads done -> stg may overwrite
#pragma unroll
    for (int nj = 0; nj < 2; ++nj) {
        int c = wc + nj * 16 + lrow;
        if (c < 64) {
            float bias = bk[c];
#pragma unroll
            for (int mi = 0; mi < 4; ++mi) {
                int p0 = mi * 16 + lgrp * 4;
                ushort4 hv;
                hv.x = bf16_rn(acc[mi][nj][0] + bias);
                hv.y = bf16_rn(acc[mi][nj][1] + bias);
                hv.z = bf16_rn(acc[mi][nj][2] + bias);
                hv.w = bf16_rn(acc[mi][nj][3] + bias);
                *(ushort4*)&stg[c * 72 + p0] = hv;
            }
        } else {
            int cv = c - 64;
#pragma unroll
            for (int mi = 0; mi < 4; ++mi) {
                int dyg = mi * 2 + (lgrp >> 1);
                float bias = bv[cv] + rpbl[cv * 8 + dyg];
                int dxb = (lgrp & 1) * 4;
#pragma unroll
                for (int rr = 0; rr < 4; ++rr) {
                    float vv = acc[mi][nj][rr] + bias;
                    stg[4608 + cv * 72 + (dxb + rr) * 8 + dyg] = bf16_rn(vv);
                }
            }
        }
    }
    __syncthreads();
    {   // write out in tile order: 64B per thread (2 planes x 64 ch x 2 halves)
        int pl = t >> 7, c = (t >> 1) & 63, half = t & 1;
        const unsigned short* src = &stg[pl * 4608 + c * 72 + half * 32];
        unsigned short* dstp = pl ? vthi : khi;
        size_t hb = ((size_t)(b * 64 + c)) << 16;
        size_t tb = pl ? (size_t)((w0 >> 3) * 2048 + (h0 >> 3) * 64)
                       : (size_t)((h0 >> 3) * 2048 + (w0 >> 3) * 64);
        unsigned short* dst = dstp + hb + tb + half * 32;
#pragma unroll
        for (int r2 = 0; r2 < 4; ++r2)
            *(short8b*)(dst + r2 * 8) = *(const short8b*)(src + r2 * 8);
    }
}

// ---------- kernel 5: MFMA attention, single-bf16 everywhere; O stored single bf16 over q
__global__ __launch_bounds__(512, 4)
void attn_mfma_kernel(unsigned short* __restrict__ qh,
                      const unsigned short* __restrict__ khig,
                      const unsigned short* __restrict__ vthig) {
    __shared__ char sm[68608];
    unsigned short* qs = (unsigned short*)sm;    // [64][264] single plane
    unsigned short* ps = (unsigned short*)sm;    // overlays q after phase 1
    float* ost = (float*)sm;                     // [64][260] overlays P after phase 3
    float* reds = (float*)(sm + 66560);          // [8][64]

    int t = threadIdx.x;
    int lane = t & 63, w = t >> 6;
    int lrow = lane & 15, lgrp = lane >> 4;
    int wc = w * 32;

    int bid = blockIdx.x;
    int xcd = bid & 7, r = bid >> 3;
    int head = xcd * 64 + (r >> 2), rt = r & 3;
    size_t qfb = ((size_t)head << 16) + (size_t)rt * 64 * 256;
    const unsigned short* kh = khig + ((size_t)head << 16);
    const unsigned short* vth = vthig + ((size_t)head << 16);

    {
        int row = t >> 3, cb = (t & 7) * 32;
        const unsigned short* s0 = qh + qfb + row * 256 + cb;
        unsigned short* d0 = &qs[row * 264 + cb];
#pragma unroll
        for (int u = 0; u < 4; ++u)
            *(short8b*)(d0 + u * 8) = *(const short8b*)(s0 + u * 8);
    }
    __syncthreads();

    int j0r = wc + lrow, j1r = wc + 16 + lrow;
    size_t jo0 = (size_t)((j0r >> 3) * 2048 + (j0r & 7) * 8);
    size_t jo1 = (size_t)((j1r >> 3) * 2048 + (j1r & 7) * 8);

    f32x4 acc[4][2];
#pragma unroll
    for (int mi = 0; mi < 4; ++mi)
#pragma unroll
        for (int nj = 0; nj < 2; ++nj) acc[mi][nj] = (f32x4){0.f, 0.f, 0.f, 0.f};

#pragma unroll
    for (int s = 0; s < 8; ++s) {
        int k0 = s * 32 + lgrp * 8;
        size_t doff = (size_t)((s * 4 + lgrp) * 64);
        short8b bh0 = *(const short8b*)(kh + jo0 + doff);
        short8b bh1 = *(const short8b*)(kh + jo1 + doff);
#pragma unroll
        for (int mi = 0; mi < 4; ++mi) {
            short8b ah = *(short8b*)&qs[(mi * 16 + lrow) * 264 + k0];
            acc[mi][0] = MFMA16(ah, bh0, acc[mi][0], 0, 0, 0);
            acc[mi][1] = MFMA16(ah, bh1, acc[mi][1], 0, 0, 0);
        }
    }
    __syncthreads();

#pragma unroll
    for (int mi = 0; mi < 4; ++mi)
#pragma unroll
        for (int rr = 0; rr < 4; ++rr) {
            int row = mi * 16 + lgrp * 4 + rr;
            float p0 = __expf(acc[mi][0][rr]);
            float p1 = __expf(acc[mi][1][rr]);
            ps[row * 264 + wc + lrow] = bf16_rn(p0);
            ps[row * 264 + wc + 16 + lrow] = bf16_rn(p1);
            float ls = p0 + p1;
            ls += __shfl_xor(ls, 1);
            ls += __shfl_xor(ls, 2);
            ls += __shfl_xor(ls, 4);
            ls += __shfl_xor(ls, 8);
            if (lrow == 0) reds[w * 64 + row] = ls;
        }
    __syncthreads();

#pragma unroll
    for (int mi = 0; mi < 4; ++mi)
#pragma unroll
        for (int nd = 0; nd < 2; ++nd) acc[mi][nd] = (f32x4){0.f, 0.f, 0.f, 0.f};

#pragma unroll
    for (int jc = 0; jc < 8; ++jc) {
        int j0 = jc * 32 + lgrp * 8;
        size_t joff = (size_t)((jc * 4 + lgrp) * 64);
        short8b vh0 = *(const short8b*)(vth + jo0 + joff);
        short8b vh1 = *(const short8b*)(vth + jo1 + joff);
#pragma unroll
        for (int mi = 0; mi < 4; ++mi) {
            short8b pa = *(short8b*)&ps[(mi * 16 + lrow) * 264 + j0];
            acc[mi][0] = MFMA16(pa, vh0, acc[mi][0], 0, 0, 0);
            acc[mi][1] = MFMA16(pa, vh1, acc[mi][1], 0, 0, 0);
        }
    }
    __syncthreads();

    float invl[4][4];
#pragma unroll
    for (int mi = 0; mi < 4; ++mi)
#pragma unroll
        for (int rr = 0; rr < 4; ++rr) {
            int row = mi * 16 + lgrp * 4 + rr;
            float l = 0.f;
#pragma unroll
            for (int ww = 0; ww < 8; ++ww) l += reds[ww * 64 + row];
            invl[mi][rr] = 1.f / l;
        }
#pragma unroll
    for (int mi = 0; mi < 4; ++mi)
#pragma unroll
        for (int nd = 0; nd < 2; ++nd)
#pragma unroll
            for (int rr = 0; rr < 4; ++rr)
                ost[(mi * 16 + lgrp * 4 + rr) * 260 + wc + nd * 16 + lrow] =
                    acc[mi][nd][rr] * invl[mi][rr];
    __syncthreads();
#pragma unroll
    for (int it = 0; it < 8; ++it) {
        int id = it * 512 + t;
        int row = id >> 6, col4 = (id & 63) * 4;
        float4 vv = *(float4*)&ost[row * 260 + col4];
        ushort4 hv;
        hv.x = bf16_rn(vv.x); hv.y = bf16_rn(vv.y);
        hv.z = bf16_rn(vv.z); hv.w = bf16_rn(vv.w);
        *(ushort4*)(qh + qfb + row * 256 + col4) = hv;
    }
}

// ---------- kernel 6: final 1x1 conv via MFMA; fp32 out staged in LDS -> 64B-chunk stores
__global__ __launch_bounds__(256)
void convout_kernel(const unsigned short* __restrict__ oh,
                    const unsigned short* __restrict__ wh, const unsigned short* __restrict__ wl,
                    const float* __restrict__ bias, float* __restrict__ out) {
    __shared__ char smem[17408];             // a_s [64][72] bf16 (9216 B) -> ost [64][68] f32 overlay
    unsigned short* a_s = (unsigned short*)smem;
    float* ost = (float*)smem;
    int t = threadIdx.x;
    int p = t & 63, w = t >> 6;
    size_t pix0 = (size_t)blockIdx.x * 64;
    {
        const unsigned short* s0 = oh + (pix0 + p) * 64 + w * 16;
        *(short8b*)&a_s[p * 72 + w * 16]     = *(const short8b*)(s0);
        *(short8b*)&a_s[p * 72 + w * 16 + 8] = *(const short8b*)(s0 + 8);
    }
    __syncthreads();
    int lrow = t & 15, lgrp = (t & 63) >> 4;
    int c = w * 16 + lrow;
    f32x4 acc[4];
#pragma unroll
    for (int mi = 0; mi < 4; ++mi) acc[mi] = (f32x4){0.f, 0.f, 0.f, 0.f};
#pragma unroll
    for (int dk = 0; dk < 2; ++dk) {
        int k0 = dk * 32 + lgrp * 8;
        short8b bh = *(const short8b*)(wh + c * 64 + k0);
        short8b bl = *(const short8b*)(wl + c * 64 + k0);
#pragma unroll
        for (int mi = 0; mi < 4; ++mi) {
            int r = mi * 16 + lrow;
            short8b ah = *(short8b*)&a_s[r * 72 + k0];
            acc[mi] = MFMA16(ah, bh, acc[mi], 0, 0, 0);
            acc[mi] = MFMA16(ah, bl, acc[mi], 0, 0, 0);
        }
    }
    float bb = bias[c];
    __syncthreads();   // a_s reads done -> ost overlay
#pragma unroll
    for (int mi = 0; mi < 4; ++mi)
#pragma unroll
        for (int rr = 0; rr < 4; ++rr)
            ost[(mi * 16 + lgrp * 4 + rr) * 68 + c] = acc[mi][rr] + bb;
    __syncthreads();
    {   // 64B-chunk coalesced stores: thread (px = t>>2, qr = t&3)
        int px = t >> 2, qr = t & 3;
        const float* src = &ost[px * 68 + qr * 16];
        float* dst = out + (pix0 + px) * 64 + qr * 16;
#pragma unroll
        for (int u4 = 0; u4 < 4; ++u4)
            *(float4*)(dst + u4 * 4) = *(const float4*)(src + u4 * 4);
    }
}

extern "C" void kernel_launch(void* const* d_in, const int* in_sizes, int n_in,
                              void* d_out, int out_size, void* d_ws, size_t ws_size,
                              hipStream_t stream) {
    const float* x     = (const float*)d_in[0];
    const float* Wq    = (const float*)d_in[1];
    const float* bq    = (const float*)d_in[2];
    const float* Wk    = (const float*)d_in[3];
    const float* bk    = (const float*)d_in[4];
    const float* Wv    = (const float*)d_in[5];
    const float* bv    = (const float*)d_in[6];
    const float* Woff1 = (const float*)d_in[7];
    const float* boff1 = (const float*)d_in[8];
    const float* Woff2 = (const float*)d_in[9];
    const float* rpb   = (const float*)d_in[10];
    const float* Wout  = (const float*)d_in[11];
    const float* bout  = (const float*)d_in[12];
    float* out = (float*)d_out;

    char* wsb = (char*)d_ws;
    unsigned short* qh  = (unsigned short*)wsb;                 // 64MB (q -> O in place)
    unsigned short* ql  = qh + (size_t)NPIX * 64;               // 64MB (proj scratch)
    unsigned short* khi = ql + (size_t)NPIX * 64;               // 64MB (tiled)
    unsigned short* klo = khi + (size_t)NPIX * 64;              // 64MB (unused)
    unsigned short* vthi = klo + (size_t)NPIX * 64;             // 64MB (tiled, transposed)
    unsigned short* xb16 = vthi + (size_t)NPIX * 64;            // 64MB (bf16 copy of x)
    float* coords = (float*)(xb16 + (size_t)NPIX * 64);         // 4MB
    float* wcomb  = coords + (size_t)NPIX * 2;                  // 3200
    float* bcomb  = wcomb + 3200;                               // 2
    float* bcat   = bcomb + 2;                                  // 128
    unsigned short* wcath = (unsigned short*)(bcat + 128);      // 8192
    unsigned short* wcatl = wcath + 8192;
    unsigned short* wkvh  = wcatl + 8192;                       // 8192
    unsigned short* wkvl  = wkvh + 8192;
    unsigned short* wouth = wkvl + 8192;                        // 4096
    unsigned short* woutl = wouth + 4096;
    unsigned short* proj = ql;   // bf16 proj scratch, consumed before attn

    build_wcomb_kernel<<<13, 256, 0, stream>>>(Woff1, boff1, Woff2, wcomb, bcomb);
    build_wcat_kernel<<<33, 256, 0, stream>>>(Wq, bq, wcomb, wcath, wcatl, bcat);
    build_wfixed_kernel<<<48, 256, 0, stream>>>(Wk, Wv, Wout, wkvh, wkvl, wouth, woutl);
    convqp_kernel<<<NPIX / 64, 256, 0, stream>>>(x, wcath, wcatl, bcat, qh, proj, xb16);
    offset_gather_kernel<<<dim3(256, 8), 256, 0, stream>>>(proj, bcomb, (float2*)coords);
    sample_kv_kernel<<<NPIX / 64, 256, 0, stream>>>(xb16, (const float2*)coords, wkvh, wkvl,
                                                    bk, bv, rpb, khi, vthi);
    attn_mfma_kernel<<<2048, 512, 0, stream>>>(qh, khi, vthi);
    convout_kernel<<<NPIX / 64, 256, 0, stream>>>(qh, wouth, woutl, bout, out);
}

// Round 20
// 324.322 us; speedup vs baseline: 1.0593x; 1.0593x over previous
//
#include <hip/hip_runtime.h>
#include <math.h>

#define NPIX 524288   // 8*256*256

typedef __attribute__((ext_vector_type(8))) short short8b;
typedef __attribute__((ext_vector_type(4))) float f32x4;
#define MFMA16 __builtin_amdgcn_mfma_f32_16x16x32_bf16

__device__ inline unsigned short bf16_rn(float x) {
    unsigned u = __float_as_uint(x);
    unsigned r = (u + 0x7FFFu + ((u >> 16) & 1u)) >> 16;
    return (unsigned short)r;
}
__device__ inline float bf16_f(unsigned short h) {
    return __uint_as_float(((unsigned)h) << 16);
}
// truncation split for weight hi/lo pairs
__device__ inline void tsplit1(float a, unsigned short& h, unsigned short& l) {
    unsigned u = __float_as_uint(a);
    h = (unsigned short)(u >> 16);
    float r = a - __uint_as_float(u & 0xFFFF0000u);
    l = (unsigned short)(__float_as_uint(r) >> 16);
}

// ---------- kernel 1a: collapse offset head
__global__ void build_wcomb_kernel(const float* __restrict__ Woff1,
                                   const float* __restrict__ boff1,
                                   const float* __restrict__ Woff2,
                                   float* __restrict__ wcomb,
                                   float* __restrict__ bcomb) {
    int idx = blockIdx.x * 256 + threadIdx.x;
    if (idx < 2 * 64 * 25) {
        int p = idx / 1600;
        int rest = idx - p * 1600;
        float s = 0.f;
        for (int cm = 0; cm < 64; ++cm)
            s += Woff2[p * 64 + cm] * Woff1[cm * 1600 + rest];
        wcomb[idx] = s;
    }
    if (idx < 2) {
        float s = 0.f;
        for (int cm = 0; cm < 64; ++cm) s += Woff2[idx * 64 + cm] * boff1[cm];
        bcomb[idx] = s;
    }
}

// ---------- kernel 1b: Wcat[128][64] = [0.125*Wq ; Wproj@Wq ; 0] as bf16 hi/lo + fp32 bcat
__global__ void build_wcat_kernel(const float* __restrict__ Wq, const float* __restrict__ bq,
                                  const float* __restrict__ wcomb,
                                  unsigned short* __restrict__ wcath,
                                  unsigned short* __restrict__ wcatl,
                                  float* __restrict__ bcat) {
    int idx = blockIdx.x * 256 + threadIdx.x;
    if (idx < 8192) {
        int r = idx >> 6, c = idx & 63;
        float v = 0.f;
        if (r < 64) v = Wq[r * 64 + c] * 0.125f;
        else if (r < 114) {
            int ch = r - 64, p = ch / 25, tap = ch % 25;
            for (int cin = 0; cin < 64; ++cin)
                v += wcomb[p * 1600 + cin * 25 + tap] * Wq[cin * 64 + c];
        }
        unsigned short hh, ll;
        tsplit1(v, hh, ll);
        wcath[idx] = hh;
        wcatl[idx] = ll;
    }
    if (idx >= 8192 && idx < 8192 + 128) {
        int r = idx - 8192;
        float v = 0.f;
        if (r < 64) v = bq[r] * 0.125f;
        else if (r < 114) {
            int ch = r - 64, p = ch / 25, tap = ch % 25;
            for (int cin = 0; cin < 64; ++cin)
                v += wcomb[p * 1600 + cin * 25 + tap] * bq[cin];
        }
        bcat[r] = v;
    }
}

// ---------- kernel 1c: fixed weights -> bf16 hi/lo planes
__global__ void build_wfixed_kernel(const float* __restrict__ Wk, const float* __restrict__ Wv,
                                    const float* __restrict__ Wout,
                                    unsigned short* __restrict__ wkvh, unsigned short* __restrict__ wkvl,
                                    unsigned short* __restrict__ wouth, unsigned short* __restrict__ woutl) {
    int idx = blockIdx.x * 256 + threadIdx.x;
    if (idx < 8192) {
        float v = (idx < 4096) ? Wk[idx] : Wv[idx - 4096];
        unsigned short hh, ll;
        tsplit1(v, hh, ll);
        wkvh[idx] = hh;
        wkvl[idx] = ll;
    } else if (idx < 12288) {
        float v = Wout[idx - 8192];
        unsigned short hh, ll;
        tsplit1(v, hh, ll);
        wouth[idx - 8192] = hh;
        woutl[idx - 8192] = ll;
    }
}

// ---------- kernel 2: fused q + proj conv via MFMA; emits xb16; q/proj staged in LDS
// for 64B-chunk coalesced plane writes
__global__ __launch_bounds__(256)
void convqp_kernel(const float* __restrict__ in, const unsigned short* __restrict__ wh,
                   const unsigned short* __restrict__ wl, const float* __restrict__ bcat,
                   unsigned short* __restrict__ qh, unsigned short* __restrict__ projout,
                   unsigned short* __restrict__ xb16) {
    __shared__ unsigned short lds[8704];     // 17408 B
    unsigned short* a_s  = lds;              // [64][72] (input staging + MFMA A)
    unsigned short* stg2 = lds;              // [114][68] overlay after MFMA
    int t = threadIdx.x;
    int p = t & 63, w = t >> 6;
    int pix0 = blockIdx.x * 64;
    {
        const float4* src = (const float4*)(in + (size_t)(pix0 + p) * 64 + w * 16);
#pragma unroll
        for (int u4 = 0; u4 < 4; ++u4) {
            float4 v = src[u4];
            ushort4 hv;
            hv.x = bf16_rn(v.x); hv.y = bf16_rn(v.y);
            hv.z = bf16_rn(v.z); hv.w = bf16_rn(v.w);
            *(ushort4*)&a_s[p * 72 + w * 16 + u4 * 4] = hv;
        }
    }
    __syncthreads();
    {   // coalesced xb16 store: thread (pgx = t>>2, wgx = t&3) writes 32B
        int pgx = t >> 2, wgx = t & 3;
        const unsigned short* srcx = &a_s[pgx * 72 + wgx * 16];
        unsigned short* dstx = xb16 + (size_t)(pix0 + pgx) * 64 + wgx * 16;
        *(short8b*)(dstx)     = *(const short8b*)(srcx);
        *(short8b*)(dstx + 8) = *(const short8b*)(srcx + 8);
    }
    int lrow = t & 15, lgrp = (t & 63) >> 4;
    int wc = w * 32;
    f32x4 acc[4][2];
#pragma unroll
    for (int mi = 0; mi < 4; ++mi)
#pragma unroll
        for (int nj = 0; nj < 2; ++nj) acc[mi][nj] = (f32x4){0.f, 0.f, 0.f, 0.f};
#pragma unroll
    for (int dk = 0; dk < 2; ++dk) {
        int k0 = dk * 32 + lgrp * 8;
        short8b bh[2], bl[2];
#pragma unroll
        for (int nj = 0; nj < 2; ++nj) {
            int c = wc + nj * 16 + lrow;
            bh[nj] = *(const short8b*)(wh + c * 64 + k0);
            bl[nj] = *(const short8b*)(wl + c * 64 + k0);
        }
#pragma unroll
        for (int mi = 0; mi < 4; ++mi) {
            int r = mi * 16 + lrow;
            short8b ah = *(short8b*)&a_s[r * 72 + k0];
#pragma unroll
            for (int nj = 0; nj < 2; ++nj) {
                acc[mi][nj] = MFMA16(ah, bh[nj], acc[mi][nj], 0, 0, 0);
                acc[mi][nj] = MFMA16(ah, bl[nj], acc[mi][nj], 0, 0, 0);
            }
        }
    }
    __syncthreads();   // all a_s reads done -> stg2 may overwrite
#pragma unroll
    for (int nj = 0; nj < 2; ++nj) {
        int c = wc + nj * 16 + lrow;
        if (c < 114) {
            float bias = bcat[c];
#pragma unroll
            for (int mi = 0; mi < 4; ++mi) {
                ushort4 hv;
                hv.x = bf16_rn(acc[mi][nj][0] + bias);
                hv.y = bf16_rn(acc[mi][nj][1] + bias);
                hv.z = bf16_rn(acc[mi][nj][2] + bias);
                hv.w = bf16_rn(acc[mi][nj][3] + bias);
                *(ushort4*)&stg2[c * 68 + mi * 16 + lgrp * 4] = hv;
            }
        }
    }
    __syncthreads();
    if (t < 228) {   // 64B-chunk coalesced plane writes
        int c = t >> 1, half = t & 1;
        int b = pix0 >> 16, hw0 = pix0 & 65535;
        const unsigned short* src = &stg2[c * 68 + half * 32];
        unsigned short* dst = (c < 64)
            ? qh + (((size_t)(b * 64 + c)) << 16) + hw0 + half * 32
            : projout + (((size_t)(b * 50 + (c - 64))) << 16) + hw0 + half * 32;
#pragma unroll
        for (int r2 = 0; r2 < 4; ++r2)
            *(short8b*)(dst + r2 * 8) = *(const short8b*)(src + r2 * 8);
    }
}

// ---------- kernel 3: offset via 25-tap shift-add over bf16 proj planes -> sample coords
__global__ __launch_bounds__(256)
void offset_gather_kernel(const unsigned short* __restrict__ proj, const float* __restrict__ bcomb,
                          float2* __restrict__ coords) {
    int x = threadIdx.x, y = blockIdx.x, b = blockIdx.y;
    const unsigned short* pb = proj + (((size_t)b * 50) << 16);
    float a0 = bcomb[0], a1 = bcomb[1];
#pragma unroll
    for (int ky = 0; ky < 5; ++ky) {
        int yy = y + ky - 2;
        if (yy < 0 || yy >= 256) continue;
#pragma unroll
        for (int kx = 0; kx < 5; ++kx) {
            int xx = x + kx - 2;
            if (xx < 0 || xx >= 256) continue;
            int tap = ky * 5 + kx;
            size_t off = (size_t)yy * 256 + xx;
            a0 += bf16_f(pb[((size_t)tap << 16) + off]);
            a1 += bf16_f(pb[((size_t)(25 + tap) << 16) + off]);
        }
    }
    float ox = tanhf(a0) * 5.f, oy = tanhf(a1) * 5.f;
    float vgx = (float)x + ox, vgy = (float)y + oy;
    float ix = vgx * (256.f / 255.f) - 0.5f;
    float iy = vgy * (256.f / 255.f) - 0.5f;
    coords[(((size_t)b) << 16) + y * 256 + x] = make_float2(ix, iy);
}

// ---------- kernel 4: 8x8-patch bilinear sample (bf16 x) + k/v convs via MFMA
__global__ __launch_bounds__(256)
void sample_kv_kernel(const unsigned short* __restrict__ xb16, const float2* __restrict__ coords,
                      const unsigned short* __restrict__ wh, const unsigned short* __restrict__ wl,
                      const float* __restrict__ bk, const float* __restrict__ bv,
                      const float* __restrict__ rpb,
                      unsigned short* __restrict__ khi, unsigned short* __restrict__ vthi) {
    __shared__ char smem[18432 + 2048];
    unsigned short* a_s = (unsigned short*)smem;             // [64][72] single plane
    unsigned short* stg = (unsigned short*)smem;             // 2 x [64][72] overlays a after barrier
    float* rpbl = (float*)(smem + 18432);                    // [64 c][8 h]

    int t = threadIdx.x;
    int b = blockIdx.x >> 10, pidx = blockIdx.x & 1023;
    int h0 = (pidx >> 5) * 8, w0 = (pidx & 31) * 8;
    int w = t >> 6;
    {   // stage rpb slice
        int i0 = t * 2;
        rpbl[i0]     = rpb[(i0 >> 3) * 256 + h0 + (i0 & 7)];
        rpbl[i0 + 1] = rpb[((i0 + 1) >> 3) * 256 + h0 + ((i0 + 1) & 7)];
    }
    {   // gather from bf16 x: pg = pixel (t>>2), wg = chan-quarter (t&3)
        int pg = t >> 2, wg = t & 3;
        int dyg = pg >> 3, dxg = pg & 7;
        int hwg = (h0 + dyg) * 256 + (w0 + dxg);
        float2 cc = coords[(((size_t)b) << 16) + hwg];
        float ix0f = floorf(cc.x), iy0f = floorf(cc.y);
        float wx1 = cc.x - ix0f, wy1 = cc.y - iy0f;
        float wx0 = 1.f - wx1, wy0 = 1.f - wy1;
        int ix0 = (int)ix0f, iy0 = (int)iy0f;
        float s[16];
#pragma unroll
        for (int u = 0; u < 16; ++u) s[u] = 0.f;
        const unsigned short* xb = xb16 + ((((size_t)b) << 16) << 6) + wg * 16;
        int cxs[4] = {ix0, ix0 + 1, ix0, ix0 + 1};
        int cys[4] = {iy0, iy0, iy0 + 1, iy0 + 1};
        float ws4[4] = {wx0 * wy0, wx1 * wy0, wx0 * wy1, wx1 * wy1};
#pragma unroll
        for (int cr = 0; cr < 4; ++cr) {
            int cx = cxs[cr], cy = cys[cr];
            if (cx >= 0 && cx < 256 && cy >= 0 && cy < 256) {
                float wgt = ws4[cr];
                const short8b* sp = (const short8b*)(xb + ((size_t)(cy * 256 + cx) << 6));
                short8b v0 = sp[0];
                short8b v1 = sp[1];
#pragma unroll
                for (int u = 0; u < 8; ++u) {
                    s[u]     += wgt * bf16_f((unsigned short)v0[u]);
                    s[u + 8] += wgt * bf16_f((unsigned short)v1[u]);
                }
            }
        }
#pragma unroll
        for (int u4 = 0; u4 < 4; ++u4) {
            ushort4 hv;
            hv.x = bf16_rn(s[u4 * 4]);     hv.y = bf16_rn(s[u4 * 4 + 1]);
            hv.z = bf16_rn(s[u4 * 4 + 2]); hv.w = bf16_rn(s[u4 * 4 + 3]);
            *(ushort4*)&a_s[pg * 72 + wg * 16 + u4 * 4] = hv;
        }
    }
    __syncthreads();
    int lrow = t & 15, lgrp = (t & 63) >> 4;
    int wc = w * 32;
    f32x4 acc[4][2];
#pragma unroll
    for (int mi = 0; mi < 4; ++mi)
#pragma unroll
        for (int nj = 0; nj < 2; ++nj) acc[mi][nj] = (f32x4){0.f, 0.f, 0.f, 0.f};
#pragma unroll
    for (int dk = 0; dk < 2; ++dk) {
        int k0 = dk * 32 + lgrp * 8;
        short8b bh[2], bl[2];
#pragma unroll
        for (int nj = 0; nj < 2; ++nj) {
            int c = wc + nj * 16 + lrow;
            bh[nj] = *(const short8b*)(wh + c * 64 + k0);
            bl[nj] = *(const short8b*)(wl + c * 64 + k0);
        }
#pragma unroll
        for (int mi = 0; mi < 4; ++mi) {
            int r = mi * 16 + lrow;
            short8b ah = *(short8b*)&a_s[r * 72 + k0];
#pragma unroll
            for (int nj = 0; nj < 2; ++nj) {
                acc[mi][nj] = MFMA16(ah, bh[nj], acc[mi][nj], 0, 0, 0);
                acc[mi][nj] = MFMA16(ah, bl[nj], acc[mi][nj], 0, 0, 0);
            }
        }
    }
    __syncthreads();   // a reads done -> stg may overwrite
#pragma unroll
    for (int nj = 0; nj < 2; ++nj) {
        int c = wc + nj * 16 + lrow;
        if (c < 64) {
            float bias = bk[c];
#pragma unroll
            for (int mi = 0; mi < 4; ++mi) {
                int p0 = mi * 16 + lgrp * 4;
                ushort4 hv;
                hv.x = bf16_rn(acc[mi][nj][0] + bias);
                hv.y = bf16_rn(acc[mi][nj][1] + bias);
                hv.z = bf16_rn(acc[mi][nj][2] + bias);
                hv.w = bf16_rn(acc[mi][nj][3] + bias);
                *(ushort4*)&stg[c * 72 + p0] = hv;
            }
        } else {
            int cv = c - 64;
#pragma unroll
            for (int mi = 0; mi < 4; ++mi) {
                int dyg = mi * 2 + (lgrp >> 1);
                float bias = bv[cv] + rpbl[cv * 8 + dyg];
                int dxb = (lgrp & 1) * 4;
#pragma unroll
                for (int rr = 0; rr < 4; ++rr) {
                    float vv = acc[mi][nj][rr] + bias;
                    stg[4608 + cv * 72 + (dxb + rr) * 8 + dyg] = bf16_rn(vv);
                }
            }
        }
    }
    __syncthreads();
    {   // write out in tile order: 64B per thread (2 planes x 64 ch x 2 halves)
        int pl = t >> 7, c = (t >> 1) & 63, half = t & 1;
        const unsigned short* src = &stg[pl * 4608 + c * 72 + half * 32];
        unsigned short* dstp = pl ? vthi : khi;
        size_t hb = ((size_t)(b * 64 + c)) << 16;
        size_t tb = pl ? (size_t)((w0 >> 3) * 2048 + (h0 >> 3) * 64)
                       : (size_t)((h0 >> 3) * 2048 + (w0 >> 3) * 64);
        unsigned short* dst = dstp + hb + tb + half * 32;
#pragma unroll
        for (int r2 = 0; r2 < 4; ++r2)
            *(short8b*)(dst + r2 * 8) = *(const short8b*)(src + r2 * 8);
    }
}

// ---------- kernel 5: MFMA attention, single-bf16 everywhere; O stored single bf16 over q
__global__ __launch_bounds__(512, 4)
void attn_mfma_kernel(unsigned short* __restrict__ qh,
                      const unsigned short* __restrict__ khig,
                      const unsigned short* __restrict__ vthig) {
    __shared__ char sm[68608];
    unsigned short* qs = (unsigned short*)sm;    // [64][264] single plane
    unsigned short* ps = (unsigned short*)sm;    // overlays q after phase 1
    float* ost = (float*)sm;                     // [64][260] overlays P after phase 3
    float* reds = (float*)(sm + 66560);          // [8][64]

    int t = threadIdx.x;
    int lane = t & 63, w = t >> 6;
    int lrow = lane & 15, lgrp = lane >> 4;
    int wc = w * 32;

    int bid = blockIdx.x;
    int xcd = bid & 7, r = bid >> 3;
    int head = xcd * 64 + (r >> 2), rt = r & 3;
    size_t qfb = ((size_t)head << 16) + (size_t)rt * 64 * 256;
    const unsigned short* kh = khig + ((size_t)head << 16);
    const unsigned short* vth = vthig + ((size_t)head << 16);

    {
        int row = t >> 3, cb = (t & 7) * 32;
        const unsigned short* s0 = qh + qfb + row * 256 + cb;
        unsigned short* d0 = &qs[row * 264 + cb];
#pragma unroll
        for (int u = 0; u < 4; ++u)
            *(short8b*)(d0 + u * 8) = *(const short8b*)(s0 + u * 8);
    }
    __syncthreads();

    int j0r = wc + lrow, j1r = wc + 16 + lrow;
    size_t jo0 = (size_t)((j0r >> 3) * 2048 + (j0r & 7) * 8);
    size_t jo1 = (size_t)((j1r >> 3) * 2048 + (j1r & 7) * 8);

    f32x4 acc[4][2];
#pragma unroll
    for (int mi = 0; mi < 4; ++mi)
#pragma unroll
        for (int nj = 0; nj < 2; ++nj) acc[mi][nj] = (f32x4){0.f, 0.f, 0.f, 0.f};

#pragma unroll
    for (int s = 0; s < 8; ++s) {
        int k0 = s * 32 + lgrp * 8;
        size_t doff = (size_t)((s * 4 + lgrp) * 64);
        short8b bh0 = *(const short8b*)(kh + jo0 + doff);
        short8b bh1 = *(const short8b*)(kh + jo1 + doff);
#pragma unroll
        for (int mi = 0; mi < 4; ++mi) {
            short8b ah = *(short8b*)&qs[(mi * 16 + lrow) * 264 + k0];
            acc[mi][0] = MFMA16(ah, bh0, acc[mi][0], 0, 0, 0);
            acc[mi][1] = MFMA16(ah, bh1, acc[mi][1], 0, 0, 0);
        }
    }
    __syncthreads();

#pragma unroll
    for (int mi = 0; mi < 4; ++mi)
#pragma unroll
        for (int rr = 0; rr < 4; ++rr) {
            int row = mi * 16 + lgrp * 4 + rr;
            float p0 = __expf(acc[mi][0][rr]);
            float p1 = __expf(acc[mi][1][rr]);
            ps[row * 264 + wc + lrow] = bf16_rn(p0);
            ps[row * 264 + wc + 16 + lrow] = bf16_rn(p1);
            float ls = p0 + p1;
            ls += __shfl_xor(ls, 1);
            ls += __shfl_xor(ls, 2);
            ls += __shfl_xor(ls, 4);
            ls += __shfl_xor(ls, 8);
            if (lrow == 0) reds[w * 64 + row] = ls;
        }
    __syncthreads();

#pragma unroll
    for (int mi = 0; mi < 4; ++mi)
#pragma unroll
        for (int nd = 0; nd < 2; ++nd) acc[mi][nd] = (f32x4){0.f, 0.f, 0.f, 0.f};

#pragma unroll
    for (int jc = 0; jc < 8; ++jc) {
        int j0 = jc * 32 + lgrp * 8;
        size_t joff = (size_t)((jc * 4 + lgrp) * 64);
        short8b vh0 = *(const short8b*)(vth + jo0 + joff);
        short8b vh1 = *(const short8b*)(vth + jo1 + joff);
#pragma unroll
        for (int mi = 0; mi < 4; ++mi) {
            short8b pa = *(short8b*)&ps[(mi * 16 + lrow) * 264 + j0];
            acc[mi][0] = MFMA16(pa, vh0, acc[mi][0], 0, 0, 0);
            acc[mi][1] = MFMA16(pa, vh1, acc[mi][1], 0, 0, 0);
        }
    }
    __syncthreads();

    float invl[4][4];
#pragma unroll
    for (int mi = 0; mi < 4; ++mi)
#pragma unroll
        for (int rr = 0; rr < 4; ++rr) {
            int row = mi * 16 + lgrp * 4 + rr;
            float l = 0.f;
#pragma unroll
            for (int ww = 0; ww < 8; ++ww) l += reds[ww * 64 + row];
            invl[mi][rr] = 1.f / l;
        }
#pragma unroll
    for (int mi = 0; mi < 4; ++mi)
#pragma unroll
        for (int nd = 0; nd < 2; ++nd)
#pragma unroll
            for (int rr = 0; rr < 4; ++rr)
                ost[(mi * 16 + lgrp * 4 + rr) * 260 + wc + nd * 16 + lrow] =
                    acc[mi][nd][rr] * invl[mi][rr];
    __syncthreads();
#pragma unroll
    for (int it = 0; it < 8; ++it) {
        int id = it * 512 + t;
        int row = id >> 6, col4 = (id & 63) * 4;
        float4 vv = *(float4*)&ost[row * 260 + col4];
        ushort4 hv;
        hv.x = bf16_rn(vv.x); hv.y = bf16_rn(vv.y);
        hv.z = bf16_rn(vv.z); hv.w = bf16_rn(vv.w);
        *(ushort4*)(qh + qfb + row * 256 + col4) = hv;
    }
}

// ---------- kernel 6: final 1x1 conv via MFMA; A single bf16 (O plane), B hi/lo
__global__ __launch_bounds__(256)
void convout_kernel(const unsigned short* __restrict__ oh,
                    const unsigned short* __restrict__ wh, const unsigned short* __restrict__ wl,
                    const float* __restrict__ bias, float* __restrict__ out) {
    __shared__ unsigned short a_s[64 * 72];
    int t = threadIdx.x;
    int p = t & 63, w = t >> 6;
    size_t pix0 = (size_t)blockIdx.x * 64;
    {
        const unsigned short* s0 = oh + (pix0 + p) * 64 + w * 16;
        *(short8b*)&a_s[p * 72 + w * 16]     = *(const short8b*)(s0);
        *(short8b*)&a_s[p * 72 + w * 16 + 8] = *(const short8b*)(s0 + 8);
    }
    __syncthreads();
    int lrow = t & 15, lgrp = (t & 63) >> 4;
    int c = w * 16 + lrow;
    f32x4 acc[4];
#pragma unroll
    for (int mi = 0; mi < 4; ++mi) acc[mi] = (f32x4){0.f, 0.f, 0.f, 0.f};
#pragma unroll
    for (int dk = 0; dk < 2; ++dk) {
        int k0 = dk * 32 + lgrp * 8;
        short8b bh = *(const short8b*)(wh + c * 64 + k0);
        short8b bl = *(const short8b*)(wl + c * 64 + k0);
#pragma unroll
        for (int mi = 0; mi < 4; ++mi) {
            int r = mi * 16 + lrow;
            short8b ah = *(short8b*)&a_s[r * 72 + k0];
            acc[mi] = MFMA16(ah, bh, acc[mi], 0, 0, 0);
            acc[mi] = MFMA16(ah, bl, acc[mi], 0, 0, 0);
        }
    }
    float bb = bias[c];
#pragma unroll
    for (int mi = 0; mi < 4; ++mi) {
        size_t px0 = pix0 + mi * 16 + lgrp * 4;
#pragma unroll
        for (int rr = 0; rr < 4; ++rr)
            out[(px0 + rr) * 64 + c] = acc[mi][rr] + bb;
    }
}

extern "C" void kernel_launch(void* const* d_in, const int* in_sizes, int n_in,
                              void* d_out, int out_size, void* d_ws, size_t ws_size,
                              hipStream_t stream) {
    const float* x     = (const float*)d_in[0];
    const float* Wq    = (const float*)d_in[1];
    const float* bq    = (const float*)d_in[2];
    const float* Wk    = (const float*)d_in[3];
    const float* bk    = (const float*)d_in[4];
    const float* Wv    = (const float*)d_in[5];
    const float* bv    = (const float*)d_in[6];
    const float* Woff1 = (const float*)d_in[7];
    const float* boff1 = (const float*)d_in[8];
    const float* Woff2 = (const float*)d_in[9];
    const float* rpb   = (const float*)d_in[10];
    const float* Wout  = (const float*)d_in[11];
    const float* bout  = (const float*)d_in[12];
    float* out = (float*)d_out;

    char* wsb = (char*)d_ws;
    unsigned short* qh  = (unsigned short*)wsb;                 // 64MB (q -> O in place)
    unsigned short* ql  = qh + (size_t)NPIX * 64;               // 64MB (proj scratch)
    unsigned short* khi = ql + (size_t)NPIX * 64;               // 64MB (tiled)
    unsigned short* klo = khi + (size_t)NPIX * 64;              // 64MB (unused)
    unsigned short* vthi = klo + (size_t)NPIX * 64;             // 64MB (tiled, transposed)
    unsigned short* xb16 = vthi + (size_t)NPIX * 64;            // 64MB (bf16 copy of x)
    float* coords = (float*)(xb16 + (size_t)NPIX * 64);         // 4MB
    float* wcomb  = coords + (size_t)NPIX * 2;                  // 3200
    float* bcomb  = wcomb + 3200;                               // 2
    float* bcat   = bcomb + 2;                                  // 128
    unsigned short* wcath = (unsigned short*)(bcat + 128);      // 8192
    unsigned short* wcatl = wcath + 8192;
    unsigned short* wkvh  = wcatl + 8192;                       // 8192
    unsigned short* wkvl  = wkvh + 8192;
    unsigned short* wouth = wkvl + 8192;                        // 4096
    unsigned short* woutl = wouth + 4096;
    unsigned short* proj = ql;   // bf16 proj scratch, consumed before attn

    build_wcomb_kernel<<<13, 256, 0, stream>>>(Woff1, boff1, Woff2, wcomb, bcomb);
    build_wcat_kernel<<<33, 256, 0, stream>>>(Wq, bq, wcomb, wcath, wcatl, bcat);
    build_wfixed_kernel<<<48, 256, 0, stream>>>(Wk, Wv, Wout, wkvh, wkvl, wouth, woutl);
    convqp_kernel<<<NPIX / 64, 256, 0, stream>>>(x, wcath, wcatl, bcat, qh, proj, xb16);
    offset_gather_kernel<<<dim3(256, 8), 256, 0, stream>>>(proj, bcomb, (float2*)coords);
    sample_kv_kernel<<<NPIX / 64, 256, 0, stream>>>(xb16, (const float2*)coords, wkvh, wkvl,
                                                    bk, bv, rpb, khi, vthi);
    attn_mfma_kernel<<<2048, 512, 0, stream>>>(qh, khi, vthi);
    convout_kernel<<<NPIX / 64, 256, 0, stream>>>(qh, wouth, woutl, bout, out);
}